// Round 13
// baseline (82.147 us; speedup 1.0000x reference)
//
#include <hip/hip_runtime.h>
#include <float.h>
#include <limits.h>

typedef float4 f4;

#define HH 512
#define WW 512
#define NC 5
#define NBS 4
#define CF 128
#define DD 64
#define NN 2048
#define HW 262144
#define OUT_RW 5242880   /* 4*5*1*512*512 */
#define LN2F 0.6931471805599453f
#define INV_TEMP 14.285714285714286f

/* ws layout (bytes) */
#define WS_PEAKS  64       /* int[30]              */
#define WS_WSOFT  192      /* float[15]            */
#define WS_BTV    256      /* float[1280*3]        */
#define WS_BTI    15616    /* int[1280*3]          */
#define WS_RLOSS  31232    /* float[2048]          */
#define WS_RVALID 39424    /* int[2048]            */
#define WS_CONS   47616    /* float[2]             */
#define WS_PMM    49152    /* float[32*2048] x4    */
#define WS_PMS    (WS_PMM + 262144)
#define WS_NMM    (WS_PMS + 262144)
#define WS_NMS    (WS_NMM + 262144)

#define BETTER(v1,i1,v2,i2) ((v1) > (v2) || ((v1) == (v2) && (i1) < (i2)))
#define DOT4(a,b) ((a).x*(b).x + (a).y*(b).y + (a).z*(b).z + (a).w*(b).w)

/* merge sorted triple b into sorted triple a (top-3, jax tie-break) */
__device__ __forceinline__ void merge3(float&a0,float&a1,float&a2,int&ai0,int&ai1,int&ai2,
                                       float b0,float b1,float b2,int bi0,int bi1,int bi2){
  float c0=a0,c1=a1,c2=a2; int ci0=ai0,ci1=ai1,ci2=ai2;
  float x0,x1,x2; int y0,y1,y2;
  if (BETTER(c0,ci0,b0,bi0)){ x0=c0;y0=ci0; c0=c1;ci0=ci1; c1=c2;ci1=ci2; c2=-FLT_MAX; ci2=INT_MAX; }
  else { x0=b0;y0=bi0; b0=b1;bi0=bi1; b1=b2;bi1=bi2; b2=-FLT_MAX; bi2=INT_MAX; }
  if (BETTER(c0,ci0,b0,bi0)){ x1=c0;y1=ci0; c0=c1;ci0=ci1; }
  else { x1=b0;y1=bi0; b0=b1;bi0=bi1; }
  if (BETTER(c0,ci0,b0,bi0)){ x2=c0;y2=ci0; }
  else { x2=b0;y2=bi0; }
  a0=x0;a1=x1;a2=x2; ai0=y0;ai1=y1;ai2=y2;
}

/* ==================== KA: NMS (blocks 0..1279) || sim (blocks 1280..2303) ==================== */
__global__ __launch_bounds__(256) void ka_nms_sim(const float* __restrict__ heat,
    float* __restrict__ btv, int* __restrict__ bti,
    const float* __restrict__ E,
    const void* __restrict__ pm, const void* __restrict__ nm, const void* __restrict__ hm,
    float* __restrict__ pmm, float* __restrict__ pms,
    float* __restrict__ nmm_, float* __restrict__ nms_){
  __shared__ f4 As[64*17];
  __shared__ f4 Bs[64*16];
  int blk = blockIdx.x;
  int t = threadIdx.x;

  if (blk < 1280){
    /* ---------------- NMS: 5x5 SAME maxpool * heat, per-stripe top-3 ---------------- */
    float* svf = (float*)As;          /* [256][3] */
    int*   sii = ((int*)As) + 768;    /* [256][3] */
    int c = blk >> 8, s = blk & 255;
    const float* Hc = heat + c * HW;
    float v0=-FLT_MAX, v1=-FLT_MAX, v2=-FLT_MAX;
    int   i0=INT_MAX,  i1=INT_MAX,  i2=INT_MAX;
    int base = s * 1024;
    #pragma unroll
    for (int k = 0; k < 4; ++k){
      int p = base + t + 256*k;
      int r = p >> 9, col = p & 511;
      float v = Hc[p];
      float m = v;
      #pragma unroll
      for (int dr = -2; dr <= 2; ++dr){
        int rr = r + dr;
        if ((unsigned)rr >= (unsigned)HH) continue;
        const float* Hr = Hc + (rr << 9);
        #pragma unroll
        for (int dc = -2; dc <= 2; ++dc){
          int c2 = col + dc;
          if ((unsigned)c2 >= (unsigned)WW) continue;
          m = fmaxf(m, Hr[c2]);
        }
      }
      float nv = (v == m) ? v : 0.0f;
      if (BETTER(nv, p, v2, i2)){
        if (BETTER(nv, p, v0, i0)){ v2=v1;i2=i1; v1=v0;i1=i0; v0=nv;i0=p; }
        else if (BETTER(nv, p, v1, i1)){ v2=v1;i2=i1; v1=nv;i1=p; }
        else { v2=nv; i2=p; }
      }
    }
    svf[t*3+0]=v0; svf[t*3+1]=v1; svf[t*3+2]=v2;
    sii[t*3+0]=i0; sii[t*3+1]=i1; sii[t*3+2]=i2;
    for (int off = 128; off; off >>= 1){
      __syncthreads();
      if (t < off){
        float a0=svf[t*3], a1=svf[t*3+1], a2=svf[t*3+2];
        int   ai0=sii[t*3], ai1=sii[t*3+1], ai2=sii[t*3+2];
        int u = t + off;
        merge3(a0,a1,a2,ai0,ai1,ai2,
               svf[u*3],svf[u*3+1],svf[u*3+2], sii[u*3],sii[u*3+1],sii[u*3+2]);
        svf[t*3]=a0; svf[t*3+1]=a1; svf[t*3+2]=a2;
        sii[t*3]=ai0; sii[t*3+1]=ai1; sii[t*3+2]=ai2;
      }
    }
    if (t == 0){
      int o = blk * 3;
      btv[o]=svf[0]; btv[o+1]=svf[1]; btv[o+2]=svf[2];
      bti[o]=sii[0]; bti[o+1]=sii[1]; bti[o+2]=sii[2];
    }
    return;
  }

  /* ---------------- sim = E@E^T 64x64 tile, two-pass masked LSE partials ---------------- */
  int sb = blk - 1280;
  int bc = sb & 31, br = sb >> 5;
  int R0 = br * 64, C0 = bc * 64;
  /* inline mask-mode detect: all waves read the SAME first 64 words of nm */
  unsigned int wdet = ((const unsigned int*)nm)[t & 63];
  unsigned long long bal = __ballot(wdet > 1u && wdet != 0x3F800000u);
  int mode = (bal != 0ull) ? 2 : 0;

  const f4* E4 = (const f4*)E;
  #pragma unroll
  for (int k = 0; k < 4; ++k){
    int f = t + 256*k;
    int rr = f >> 4, dc = f & 15;
    As[rr*17 + dc] = E4[(R0 + rr)*16 + dc];
    Bs[rr*16 + (dc ^ (rr >> 2))] = E4[(C0 + rr)*16 + dc];
  }
  __syncthreads();
  int tx = t & 15, ty = t >> 4;
  float acc[4][4] = {};
  #pragma unroll 4
  for (int dc = 0; dc < 16; ++dc){
    f4 a0 = As[(ty*4+0)*17 + dc];
    f4 a1 = As[(ty*4+1)*17 + dc];
    f4 a2 = As[(ty*4+2)*17 + dc];
    f4 a3 = As[(ty*4+3)*17 + dc];
    #pragma unroll
    for (int j = 0; j < 4; ++j){
      f4 b = Bs[(tx*4+j)*16 + (dc ^ tx)];
      acc[0][j] += DOT4(a0,b);
      acc[1][j] += DOT4(a1,b);
      acc[2][j] += DOT4(a2,b);
      acc[3][j] += DOT4(a3,b);
    }
  }
  int cbase = C0 + tx*4;
  #pragma unroll
  for (int ri = 0; ri < 4; ++ri){
    int row = R0 + ty*4 + ri;
    int ofs = row * NN + cbase;
    bool p0,p1,p2,p3, n0,n1,n2,n3, h0,h1,h2,h3;
    if (mode != 2){
      int4 a = *(const int4*)((const int*)pm + ofs);
      int4 bq = *(const int4*)((const int*)nm + ofs);
      int4 cq = *(const int4*)((const int*)hm + ofs);
      p0=a.x!=0; p1=a.y!=0; p2=a.z!=0; p3=a.w!=0;
      n0=bq.x!=0; n1=bq.y!=0; n2=bq.z!=0; n3=bq.w!=0;
      h0=cq.x!=0; h1=cq.y!=0; h2=cq.z!=0; h3=cq.w!=0;
    } else {
      unsigned int a = *(const unsigned int*)((const unsigned char*)pm + ofs);
      unsigned int bq = *(const unsigned int*)((const unsigned char*)nm + ofs);
      unsigned int cq = *(const unsigned int*)((const unsigned char*)hm + ofs);
      p0=(a&0xffu)!=0; p1=(a&0xff00u)!=0; p2=(a&0xff0000u)!=0; p3=(a&0xff000000u)!=0;
      n0=(bq&0xffu)!=0; n1=(bq&0xff00u)!=0; n2=(bq&0xff0000u)!=0; n3=(bq&0xff000000u)!=0;
      h0=(cq&0xffu)!=0; h1=(cq&0xff00u)!=0; h2=(cq&0xff0000u)!=0; h3=(cq&0xff000000u)!=0;
    }
    float s0 = acc[ri][0]*INV_TEMP, s1 = acc[ri][1]*INV_TEMP,
          s2 = acc[ri][2]*INV_TEMP, s3 = acc[ri][3]*INV_TEMP;
    float xp0 = p0 ? s0 : -1e9f, xp1 = p1 ? s1 : -1e9f,
          xp2 = p2 ? s2 : -1e9f, xp3 = p3 ? s3 : -1e9f;
    float xn0 = (n0 ? s0 : -1e9f) + (h0 ? LN2F : 0.f);
    float xn1 = (n1 ? s1 : -1e9f) + (h1 ? LN2F : 0.f);
    float xn2 = (n2 ? s2 : -1e9f) + (h2 ? LN2F : 0.f);
    float xn3 = (n3 ? s3 : -1e9f) + (h3 ? LN2F : 0.f);
    float mp = fmaxf(fmaxf(xp0,xp1), fmaxf(xp2,xp3));
    float mn = fmaxf(fmaxf(xn0,xn1), fmaxf(xn2,xn3));
    #pragma unroll
    for (int off = 1; off < 16; off <<= 1){
      mp = fmaxf(mp, __shfl_xor(mp, off));
      mn = fmaxf(mn, __shfl_xor(mn, off));
    }
    float sp = __expf(xp0-mp) + __expf(xp1-mp) + __expf(xp2-mp) + __expf(xp3-mp);
    float sn = __expf(xn0-mn) + __expf(xn1-mn) + __expf(xn2-mn) + __expf(xn3-mn);
    #pragma unroll
    for (int off = 1; off < 16; off <<= 1){
      sp += __shfl_xor(sp, off);
      sn += __shfl_xor(sn, off);
    }
    if (tx == 0){
      pmm [bc*NN + row] = mp;  pms [bc*NN + row] = sp;
      nmm_[bc*NN + row] = mn;  nms_[bc*NN + row] = sn;
    }
  }
}

/* ==================== KM2: block 0 = stripe merge + MLP; blocks 1,2 = per-row LSE merge ==================== */
__global__ __launch_bounds__(1024) void km2(
    const float* __restrict__ btv, const int* __restrict__ bti,
    const float* __restrict__ fm,
    const float* __restrict__ W1, const float* __restrict__ b1,
    const float* __restrict__ W2, const float* __restrict__ b2,
    const float* __restrict__ pemb, const float* __restrict__ lsc,
    const float* __restrict__ pmm, const float* __restrict__ pms,
    const float* __restrict__ nmm_, const float* __restrict__ nms_,
    const float* __restrict__ E, const float* __restrict__ T,
    int* __restrict__ peaks, float* __restrict__ wsoft,
    float* __restrict__ rloss, int* __restrict__ rvalid, float* __restrict__ consp,
    float* __restrict__ out){
  int blk = blockIdx.x;
  int t = threadIdx.x;

  if (blk == 0){
    __shared__ int pk[30];
    __shared__ float logits[15];
    __shared__ float samp[15][CF];
    __shared__ float hbuf[15][DD];
    int wave = t >> 6, lane = t & 63;
    if (wave < 5){
      int ch = wave;
      int e0 = ch*768 + lane*3;
      float v0=btv[e0], v1=btv[e0+1], v2=btv[e0+2];
      int   i0=bti[e0], i1=bti[e0+1], i2=bti[e0+2];
      #pragma unroll
      for (int s = 1; s < 4; ++s){
        int e = ch*768 + (lane + s*64)*3;
        merge3(v0,v1,v2,i0,i1,i2, btv[e],btv[e+1],btv[e+2], bti[e],bti[e+1],bti[e+2]);
      }
      #pragma unroll
      for (int off = 32; off; off >>= 1){
        float b0=__shfl_xor(v0,off), b1=__shfl_xor(v1,off), b2=__shfl_xor(v2,off);
        int   j0=__shfl_xor(i0,off), j1=__shfl_xor(i1,off), j2=__shfl_xor(i2,off);
        merge3(v0,v1,v2,i0,i1,i2, b0,b1,b2, j0,j1,j2);
      }
      if (lane == 0){
        pk[ch*6+0]=i0>>9; pk[ch*6+1]=i0&511;
        pk[ch*6+2]=i1>>9; pk[ch*6+3]=i1&511;
        pk[ch*6+4]=i2>>9; pk[ch*6+5]=i2&511;
        #pragma unroll
        for (int q = 0; q < 6; ++q) peaks[ch*6+q] = pk[ch*6+q];
      }
    }
    __syncthreads();
    for (int u = t; u < 15*CF; u += 1024){
      int vk = u >> 7, chn = u & 127;
      int v = vk / 3;
      int r = pk[vk*2], cc = pk[vk*2+1];
      samp[vk][chn] = fm[((v*CF + chn) << 18) + (r << 9) + cc];
    }
    __syncthreads();
    if (t < 15*DD){
      int vk = t >> 6, d = t & 63;
      float acc = b1[d];
      #pragma unroll 4
      for (int chn = 0; chn < CF; ++chn) acc += samp[vk][chn] * W1[chn*DD + d];
      hbuf[vk][d] = fmaxf(acc, 0.0f);
    }
    __syncthreads();
    {
      int vk = t >> 6, d = t & 63;
      if (vk < 15){
        float acc = b2[d];
        #pragma unroll 4
        for (int e = 0; e < DD; ++e) acc += hbuf[vk][e] * W2[e*DD + d];
        float ss = acc * acc;
        #pragma unroll
        for (int off = 32; off; off >>= 1) ss += __shfl_xor(ss, off);
        float inv = 1.0f / fmaxf(sqrtf(ss), 1e-12f);
        float contrib = (acc * inv) * pemb[d];
        #pragma unroll
        for (int off = 32; off; off >>= 1) contrib += __shfl_xor(contrib, off);
        if (d == 0){
          float scale = fminf(__expf(lsc[0]), 100.0f);
          logits[vk] = contrib * scale;
        }
      }
    }
    __syncthreads();
    if (t < 5){
      int v = t;
      float l0 = logits[v*3], l1 = logits[v*3+1], l2 = logits[v*3+2];
      float mm = fmaxf(l0, fmaxf(l1, l2));
      float e0 = __expf(l0-mm), e1 = __expf(l1-mm), e2 = __expf(l2-mm);
      float sm = e0 + e1 + e2;
      wsoft[v*3] = e0/sm; wsoft[v*3+1] = e1/sm; wsoft[v*3+2] = e2/sm;
      out[OUT_RW + v*3 + 0] = l0;
      out[OUT_RW + v*3 + 1] = l1;
      out[OUT_RW + v*3 + 2] = l2;
    }
    return;
  }

  /* ---- blocks 1,2: per-row LSE merge + cons pair, 1 row/thread ---- */
  int r = (blk - 1) * 1024 + t;
  float mp = pmm[r];
  #pragma unroll 8
  for (int k = 1; k < 32; ++k) mp = fmaxf(mp, pmm[k*NN + r]);
  float sp = 0.f;
  #pragma unroll 8
  for (int k = 0; k < 32; ++k) sp += pms[k*NN + r] * __expf(pmm[k*NN + r] - mp);
  float mn = nmm_[r];
  #pragma unroll 8
  for (int k = 1; k < 32; ++k) mn = fmaxf(mn, nmm_[k*NN + r]);
  float sn = 0.f;
  #pragma unroll 8
  for (int k = 0; k < 32; ++k) sn += nms_[k*NN + r] * __expf(nmm_[k*NN + r] - mn);
  float lp = mp + __logf(sp), ln = mn + __logf(sn);
  float mm = fmaxf(lp, ln);
  float ld = mm + __logf(__expf(lp - mm) + __expf(ln - mm));
  bool valid = mp > -1e8f;
  rloss[r]  = valid ? (ld - lp) : 0.f;
  rvalid[r] = valid ? 1 : 0;
  float cs = 0.f;
  if (r < NN - 1){
    const f4* a4 = (const f4*)(E + r*DD);
    const f4* b4 = (const f4*)(E + (r+1)*DD);
    float dot=0.f, na=0.f, nb=0.f;
    #pragma unroll
    for (int q = 0; q < 16; ++q){
      f4 a = a4[q], b = b4[q];
      dot += DOT4(a,b); na += DOT4(a,a); nb += DOT4(b,b);
    }
    float cosv = dot / fmaxf(sqrtf(na)*sqrtf(nb), 1e-8f);
    float t0 = T[r*3]   - T[r*3+3];
    float t1 = T[r*3+1] - T[r*3+4];
    float t2 = T[r*3+2] - T[r*3+5];
    float td = sqrtf(t0*t0 + t1*t1 + t2*t2);
    if (td < 0.1f) cs = fmaxf(0.9f - cosv, 0.f);
  }
  __shared__ float red[1024];
  red[t] = cs;
  __syncthreads();
  for (int off = 512; off; off >>= 1){
    if (t < off) red[t] += red[t + off];
    __syncthreads();
  }
  if (t == 0) consp[blk - 1] = red[0];
}

/* ==================== K3F: reweight (blocks 0..1279) + final reduce (block 1280) ==================== */
__global__ __launch_bounds__(256) void k3f_rwfin(const float* __restrict__ heat,
    const int* __restrict__ peaks, const float* __restrict__ wsoft,
    const float* __restrict__ rloss, const int* __restrict__ rvalid,
    const float* __restrict__ consp,
    float* __restrict__ out){
  int blk = blockIdx.x;
  int t = threadIdx.x;

  if (blk < 1280){
    __shared__ float pr[3], pc[3], w3[3];
    int gid = blk * 256 + t;
    int c = gid >> 16;
    if (t < 3){
      pr[t] = (float)peaks[c*6 + t*2];
      pc[t] = (float)peaks[c*6 + t*2 + 1];
      w3[t] = wsoft[c*3 + t];
    }
    __syncthreads();
    int rem = (gid & 65535) << 2;
    int h = rem >> 9, x0 = rem & 511;
    float bias0=0.f, bias1=0.f, bias2=0.f, bias3=0.f;
    #pragma unroll
    for (int k = 0; k < 3; ++k){
      float dr = (float)h - pr[k];
      float dr2 = dr*dr;
      float w = w3[k];
      float d0 = (float)x0     - pc[k];
      float d1 = (float)(x0+1) - pc[k];
      float d2 = (float)(x0+2) - pc[k];
      float d3 = (float)(x0+3) - pc[k];
      float q0 = dr2 + d0*d0, q1 = dr2 + d1*d1, q2 = dr2 + d2*d2, q3 = dr2 + d3*d3;
      if (q0 < 324.f) bias0 += w * __expf(-q0 * (1.0f/18.0f));
      if (q1 < 324.f) bias1 += w * __expf(-q1 * (1.0f/18.0f));
      if (q2 < 324.f) bias2 += w * __expf(-q2 * (1.0f/18.0f));
      if (q3 < 324.f) bias3 += w * __expf(-q3 * (1.0f/18.0f));
    }
    #pragma unroll
    for (int b = 0; b < NBS; ++b){
      int idx = ((b*NC + c) << 18) + rem;
      f4 hv = *(const f4*)(heat + idx);
      f4 o; o.x = hv.x + bias0; o.y = hv.y + bias1; o.z = hv.z + bias2; o.w = hv.w + bias3;
      *(f4*)(out + idx) = o;
    }
    return;
  }

  /* ---- block 1280: final scalar reduce ---- */
  float s = 0.f; int cnt = 0;
  #pragma unroll
  for (int i = t; i < NN; i += 256){ s += rloss[i]; cnt += rvalid[i]; }
  float cs = (t < 2) ? consp[t] : 0.f;
  __shared__ float r1[256]; __shared__ int r2[256]; __shared__ float r3[256];
  r1[t] = s; r2[t] = cnt; r3[t] = cs;
  __syncthreads();
  for (int off = 128; off; off >>= 1){
    if (t < off){ r1[t] += r1[t+off]; r2[t] += r2[t+off]; r3[t] += r3[t+off]; }
    __syncthreads();
  }
  if (t == 0){
    int c = r2[0] > 1 ? r2[0] : 1;
    out[OUT_RW + 15] = r1[0] / (float)c;
    out[OUT_RW + 16] = r3[0] / (float)(NN - 1);
  }
}

extern "C" void kernel_launch(void* const* d_in, const int* in_sizes, int n_in,
                              void* d_out, int out_size, void* d_ws, size_t ws_size,
                              hipStream_t stream) {
  (void)in_sizes; (void)n_in; (void)out_size; (void)ws_size;
  const float* heat = (const float*)d_in[0];
  const float* fm   = (const float*)d_in[1];
  const float* pemb = (const float*)d_in[2];
  const float* W1   = (const float*)d_in[3];
  const float* b1   = (const float*)d_in[4];
  const float* W2   = (const float*)d_in[5];
  const float* b2   = (const float*)d_in[6];
  const float* lsc  = (const float*)d_in[7];
  const float* E    = (const float*)d_in[8];
  const float* T    = (const float*)d_in[9];
  const void*  pm   = d_in[10];
  const void*  nmm  = d_in[11];
  const void*  hmm  = d_in[12];
  float* out = (float*)d_out;
  char* ws = (char*)d_ws;
  int*   peaks  = (int*)(ws + WS_PEAKS);
  float* wsoft  = (float*)(ws + WS_WSOFT);
  float* btv    = (float*)(ws + WS_BTV);
  int*   bti    = (int*)(ws + WS_BTI);
  float* rloss  = (float*)(ws + WS_RLOSS);
  int*   rvalid = (int*)(ws + WS_RVALID);
  float* consp  = (float*)(ws + WS_CONS);
  float* pmm    = (float*)(ws + WS_PMM);
  float* pms    = (float*)(ws + WS_PMS);
  float* nmm2   = (float*)(ws + WS_NMM);
  float* nms2   = (float*)(ws + WS_NMS);

  hipLaunchKernelGGL(ka_nms_sim, dim3(2304), dim3(256),  0, stream,
                     heat, btv, bti, E, pm, nmm, hmm, pmm, pms, nmm2, nms2);
  hipLaunchKernelGGL(km2,        dim3(3),    dim3(1024), 0, stream,
                     btv, bti, fm, W1, b1, W2, b2, pemb, lsc,
                     pmm, pms, nmm2, nms2, E, T,
                     peaks, wsoft, rloss, rvalid, consp, out);
  hipLaunchKernelGGL(k3f_rwfin,  dim3(1281), dim3(256),  0, stream,
                     heat, peaks, wsoft, rloss, rvalid, consp, out);
}

// Round 14
// 67.536 us; speedup vs baseline: 1.2163x; 1.2163x over previous
//
#include <hip/hip_runtime.h>
#include <float.h>
#include <limits.h>

typedef float4 f4;

#define HH 512
#define WW 512
#define NC 5
#define NBS 4
#define CF 128
#define DD 64
#define NN 2048
#define HW 262144
#define OUT_RW 5242880   /* 4*5*1*512*512 */
#define LN2F 0.6931471805599453f
#define INV_TEMP 14.285714285714286f

/* ws layout (bytes) */
#define WS_PEAKS  64       /* int[30]              */
#define WS_WSOFT  192      /* float[15]            */
#define WS_BTV    256      /* float[1280*3]        */
#define WS_BTI    15616    /* int[1280*3]          */
#define WS_RLOSS  31232    /* float[2048]          */
#define WS_RVALID 39424    /* int[2048]            */
#define WS_CONS   47616    /* float[2]             */
#define WS_PMM    49152    /* float[32*2048] x4    */
#define WS_PMS    (WS_PMM + 262144)
#define WS_NMM    (WS_PMS + 262144)
#define WS_NMS    (WS_NMM + 262144)

#define BETTER(v1,i1,v2,i2) ((v1) > (v2) || ((v1) == (v2) && (i1) < (i2)))
#define DOT4(a,b) ((a).x*(b).x + (a).y*(b).y + (a).z*(b).z + (a).w*(b).w)

/* merge sorted triple b into sorted triple a (top-3, jax tie-break) */
__device__ __forceinline__ void merge3(float&a0,float&a1,float&a2,int&ai0,int&ai1,int&ai2,
                                       float b0,float b1,float b2,int bi0,int bi1,int bi2){
  float c0=a0,c1=a1,c2=a2; int ci0=ai0,ci1=ai1,ci2=ai2;
  float x0,x1,x2; int y0,y1,y2;
  if (BETTER(c0,ci0,b0,bi0)){ x0=c0;y0=ci0; c0=c1;ci0=ci1; c1=c2;ci1=ci2; c2=-FLT_MAX; ci2=INT_MAX; }
  else { x0=b0;y0=bi0; b0=b1;bi0=bi1; b1=b2;bi1=bi2; b2=-FLT_MAX; bi2=INT_MAX; }
  if (BETTER(c0,ci0,b0,bi0)){ x1=c0;y1=ci0; c0=c1;ci0=ci1; }
  else { x1=b0;y1=bi0; b0=b1;bi0=bi1; }
  if (BETTER(c0,ci0,b0,bi0)){ x2=c0;y2=ci0; }
  else { x2=b0;y2=bi0; }
  a0=x0;a1=x1;a2=x2; ai0=y0;ai1=y1;ai2=y2;
}

/* ==================== KA: NMS (blocks 0..1279) || sim (blocks 1280..2303) ==================== */
__global__ __launch_bounds__(256) void ka_nms_sim(const float* __restrict__ heat,
    float* __restrict__ btv, int* __restrict__ bti,
    const float* __restrict__ E,
    const void* __restrict__ pm, const void* __restrict__ nm, const void* __restrict__ hm,
    float* __restrict__ pmm, float* __restrict__ pms,
    float* __restrict__ nmm_, float* __restrict__ nms_){
  __shared__ f4 As[64*17];   /* 17408 B */
  __shared__ f4 Bs[64*16];   /* 16384 B */
  int blk = blockIdx.x;
  int t = threadIdx.x;

  if (blk < 1280){
    /* ---------------- separable 5x5 SAME maxpool NMS, per-stripe top-3 ---------------- */
    /* stripe = rows 2s, 2s+1 of channel c. LDS (aliased into As/Bs):
       rowbuf[6][512] in As (12288 B): rows 2s-2 .. 2s+3, OOB = -FLT_MAX
       colmax[2][516] in Bs (4128 B): vertical 5-max per output row, +2 pad each side */
    float* rowbuf = (float*)As;
    float* colmax = (float*)Bs;
    int c = blk >> 8, s = blk & 255;
    const float* Hc = heat + c * HW;

    for (int i = t; i < 3072; i += 256){
      int rowi = i >> 9, cc = i & 511;
      int grow = 2*s - 2 + rowi;
      rowbuf[i] = ((unsigned)grow < (unsigned)HH) ? Hc[(grow << 9) + cc] : -FLT_MAX;
    }
    if (t < 8){
      int rl = t >> 2, q = t & 3;
      colmax[rl*516 + (q < 2 ? q : 512 + q)] = -FLT_MAX;   /* [0],[1],[514],[515] */
    }
    __syncthreads();

    /* phase 1: vertical 5-max */
    #pragma unroll
    for (int k = 0; k < 4; ++k){
      int p = t + 256*k;
      int rl = p >> 9, cc = p & 511;
      float cm =          rowbuf[(rl+0)*512 + cc];
      cm = fmaxf(cm,      rowbuf[(rl+1)*512 + cc]);
      cm = fmaxf(cm,      rowbuf[(rl+2)*512 + cc]);
      cm = fmaxf(cm,      rowbuf[(rl+3)*512 + cc]);
      cm = fmaxf(cm,      rowbuf[(rl+4)*512 + cc]);
      colmax[rl*516 + 2 + cc] = cm;
    }
    __syncthreads();

    /* phase 2: horizontal 5-max + nms + per-thread top-3 */
    float v0=-FLT_MAX, v1=-FLT_MAX, v2=-FLT_MAX;
    int   i0=INT_MAX,  i1=INT_MAX,  i2=INT_MAX;
    #pragma unroll
    for (int k = 0; k < 4; ++k){
      int p = t + 256*k;
      int rl = p >> 9, cc = p & 511;
      float v = rowbuf[(rl+2)*512 + cc];
      int b5 = rl*516 + 2 + cc;
      float m =          colmax[b5-2];
      m = fmaxf(m,       colmax[b5-1]);
      m = fmaxf(m,       colmax[b5  ]);
      m = fmaxf(m,       colmax[b5+1]);
      m = fmaxf(m,       colmax[b5+2]);
      float nv = (v == m) ? v : 0.0f;
      int pidx = s*1024 + p;
      if (BETTER(nv, pidx, v2, i2)){
        if (BETTER(nv, pidx, v0, i0)){ v2=v1;i2=i1; v1=v0;i1=i0; v0=nv;i0=pidx; }
        else if (BETTER(nv, pidx, v1, i1)){ v2=v1;i2=i1; v1=nv;i1=pidx; }
        else { v2=nv; i2=pidx; }
      }
    }
    __syncthreads();   /* rowbuf/colmax dead; reuse As for reduce */

    float* svf = (float*)As;          /* [256][3] */
    int*   sii = ((int*)As) + 768;    /* [256][3] */
    svf[t*3+0]=v0; svf[t*3+1]=v1; svf[t*3+2]=v2;
    sii[t*3+0]=i0; sii[t*3+1]=i1; sii[t*3+2]=i2;
    for (int off = 128; off; off >>= 1){
      __syncthreads();
      if (t < off){
        float a0=svf[t*3], a1=svf[t*3+1], a2=svf[t*3+2];
        int   ai0=sii[t*3], ai1=sii[t*3+1], ai2=sii[t*3+2];
        int u = t + off;
        merge3(a0,a1,a2,ai0,ai1,ai2,
               svf[u*3],svf[u*3+1],svf[u*3+2], sii[u*3],sii[u*3+1],sii[u*3+2]);
        svf[t*3]=a0; svf[t*3+1]=a1; svf[t*3+2]=a2;
        sii[t*3]=ai0; sii[t*3+1]=ai1; sii[t*3+2]=ai2;
      }
    }
    if (t == 0){
      int o = blk * 3;
      btv[o]=svf[0]; btv[o+1]=svf[1]; btv[o+2]=svf[2];
      bti[o]=sii[0]; bti[o+1]=sii[1]; bti[o+2]=sii[2];
    }
    return;
  }

  /* ---------------- sim = E@E^T 64x64 tile, two-pass masked LSE partials ---------------- */
  int sb = blk - 1280;
  int bc = sb & 31, br = sb >> 5;
  int R0 = br * 64, C0 = bc * 64;
  /* inline mask-mode detect: all waves read the SAME first 64 words of nm */
  unsigned int wdet = ((const unsigned int*)nm)[t & 63];
  unsigned long long bal = __ballot(wdet > 1u && wdet != 0x3F800000u);
  int mode = (bal != 0ull) ? 2 : 0;

  const f4* E4 = (const f4*)E;
  #pragma unroll
  for (int k = 0; k < 4; ++k){
    int f = t + 256*k;
    int rr = f >> 4, dc = f & 15;
    As[rr*17 + dc] = E4[(R0 + rr)*16 + dc];
    Bs[rr*16 + (dc ^ (rr >> 2))] = E4[(C0 + rr)*16 + dc];
  }
  __syncthreads();
  int tx = t & 15, ty = t >> 4;
  float acc[4][4] = {};
  #pragma unroll 4
  for (int dc = 0; dc < 16; ++dc){
    f4 a0 = As[(ty*4+0)*17 + dc];
    f4 a1 = As[(ty*4+1)*17 + dc];
    f4 a2 = As[(ty*4+2)*17 + dc];
    f4 a3 = As[(ty*4+3)*17 + dc];
    #pragma unroll
    for (int j = 0; j < 4; ++j){
      f4 b = Bs[(tx*4+j)*16 + (dc ^ tx)];
      acc[0][j] += DOT4(a0,b);
      acc[1][j] += DOT4(a1,b);
      acc[2][j] += DOT4(a2,b);
      acc[3][j] += DOT4(a3,b);
    }
  }
  int cbase = C0 + tx*4;
  #pragma unroll
  for (int ri = 0; ri < 4; ++ri){
    int row = R0 + ty*4 + ri;
    int ofs = row * NN + cbase;
    bool p0,p1,p2,p3, n0,n1,n2,n3, h0,h1,h2,h3;
    if (mode != 2){
      int4 a = *(const int4*)((const int*)pm + ofs);
      int4 bq = *(const int4*)((const int*)nm + ofs);
      int4 cq = *(const int4*)((const int*)hm + ofs);
      p0=a.x!=0; p1=a.y!=0; p2=a.z!=0; p3=a.w!=0;
      n0=bq.x!=0; n1=bq.y!=0; n2=bq.z!=0; n3=bq.w!=0;
      h0=cq.x!=0; h1=cq.y!=0; h2=cq.z!=0; h3=cq.w!=0;
    } else {
      unsigned int a = *(const unsigned int*)((const unsigned char*)pm + ofs);
      unsigned int bq = *(const unsigned int*)((const unsigned char*)nm + ofs);
      unsigned int cq = *(const unsigned int*)((const unsigned char*)hm + ofs);
      p0=(a&0xffu)!=0; p1=(a&0xff00u)!=0; p2=(a&0xff0000u)!=0; p3=(a&0xff000000u)!=0;
      n0=(bq&0xffu)!=0; n1=(bq&0xff00u)!=0; n2=(bq&0xff0000u)!=0; n3=(bq&0xff000000u)!=0;
      h0=(cq&0xffu)!=0; h1=(cq&0xff00u)!=0; h2=(cq&0xff0000u)!=0; h3=(cq&0xff000000u)!=0;
    }
    float s0 = acc[ri][0]*INV_TEMP, s1 = acc[ri][1]*INV_TEMP,
          s2 = acc[ri][2]*INV_TEMP, s3 = acc[ri][3]*INV_TEMP;
    float xp0 = p0 ? s0 : -1e9f, xp1 = p1 ? s1 : -1e9f,
          xp2 = p2 ? s2 : -1e9f, xp3 = p3 ? s3 : -1e9f;
    float xn0 = (n0 ? s0 : -1e9f) + (h0 ? LN2F : 0.f);
    float xn1 = (n1 ? s1 : -1e9f) + (h1 ? LN2F : 0.f);
    float xn2 = (n2 ? s2 : -1e9f) + (h2 ? LN2F : 0.f);
    float xn3 = (n3 ? s3 : -1e9f) + (h3 ? LN2F : 0.f);
    float mp = fmaxf(fmaxf(xp0,xp1), fmaxf(xp2,xp3));
    float mn = fmaxf(fmaxf(xn0,xn1), fmaxf(xn2,xn3));
    #pragma unroll
    for (int off = 1; off < 16; off <<= 1){
      mp = fmaxf(mp, __shfl_xor(mp, off));
      mn = fmaxf(mn, __shfl_xor(mn, off));
    }
    float sp = __expf(xp0-mp) + __expf(xp1-mp) + __expf(xp2-mp) + __expf(xp3-mp);
    float sn = __expf(xn0-mn) + __expf(xn1-mn) + __expf(xn2-mn) + __expf(xn3-mn);
    #pragma unroll
    for (int off = 1; off < 16; off <<= 1){
      sp += __shfl_xor(sp, off);
      sn += __shfl_xor(sn, off);
    }
    if (tx == 0){
      pmm [bc*NN + row] = mp;  pms [bc*NN + row] = sp;
      nmm_[bc*NN + row] = mn;  nms_[bc*NN + row] = sn;
    }
  }
}

/* ==================== KM2: block 0 = stripe merge + MLP; blocks 1,2 = per-row LSE merge ==================== */
__global__ __launch_bounds__(1024) void km2(
    const float* __restrict__ btv, const int* __restrict__ bti,
    const float* __restrict__ fm,
    const float* __restrict__ W1, const float* __restrict__ b1,
    const float* __restrict__ W2, const float* __restrict__ b2,
    const float* __restrict__ pemb, const float* __restrict__ lsc,
    const float* __restrict__ pmm, const float* __restrict__ pms,
    const float* __restrict__ nmm_, const float* __restrict__ nms_,
    const float* __restrict__ E, const float* __restrict__ T,
    int* __restrict__ peaks, float* __restrict__ wsoft,
    float* __restrict__ rloss, int* __restrict__ rvalid, float* __restrict__ consp,
    float* __restrict__ out){
  int blk = blockIdx.x;
  int t = threadIdx.x;

  if (blk == 0){
    __shared__ int pk[30];
    __shared__ float logits[15];
    __shared__ float samp[15][CF];
    __shared__ float hbuf[15][DD];
    int wave = t >> 6, lane = t & 63;
    if (wave < 5){
      int ch = wave;
      int e0 = ch*768 + lane*3;
      float v0=btv[e0], v1=btv[e0+1], v2=btv[e0+2];
      int   i0=bti[e0], i1=bti[e0+1], i2=bti[e0+2];
      #pragma unroll
      for (int s = 1; s < 4; ++s){
        int e = ch*768 + (lane + s*64)*3;
        merge3(v0,v1,v2,i0,i1,i2, btv[e],btv[e+1],btv[e+2], bti[e],bti[e+1],bti[e+2]);
      }
      #pragma unroll
      for (int off = 32; off; off >>= 1){
        float b0=__shfl_xor(v0,off), b1=__shfl_xor(v1,off), b2=__shfl_xor(v2,off);
        int   j0=__shfl_xor(i0,off), j1=__shfl_xor(i1,off), j2=__shfl_xor(i2,off);
        merge3(v0,v1,v2,i0,i1,i2, b0,b1,b2, j0,j1,j2);
      }
      if (lane == 0){
        pk[ch*6+0]=i0>>9; pk[ch*6+1]=i0&511;
        pk[ch*6+2]=i1>>9; pk[ch*6+3]=i1&511;
        pk[ch*6+4]=i2>>9; pk[ch*6+5]=i2&511;
        #pragma unroll
        for (int q = 0; q < 6; ++q) peaks[ch*6+q] = pk[ch*6+q];
      }
    }
    __syncthreads();
    for (int u = t; u < 15*CF; u += 1024){
      int vk = u >> 7, chn = u & 127;
      int v = vk / 3;
      int r = pk[vk*2], cc = pk[vk*2+1];
      samp[vk][chn] = fm[((v*CF + chn) << 18) + (r << 9) + cc];
    }
    __syncthreads();
    if (t < 15*DD){
      int vk = t >> 6, d = t & 63;
      float acc = b1[d];
      #pragma unroll 4
      for (int chn = 0; chn < CF; ++chn) acc += samp[vk][chn] * W1[chn*DD + d];
      hbuf[vk][d] = fmaxf(acc, 0.0f);
    }
    __syncthreads();
    {
      int vk = t >> 6, d = t & 63;
      if (vk < 15){
        float acc = b2[d];
        #pragma unroll 4
        for (int e = 0; e < DD; ++e) acc += hbuf[vk][e] * W2[e*DD + d];
        float ss = acc * acc;
        #pragma unroll
        for (int off = 32; off; off >>= 1) ss += __shfl_xor(ss, off);
        float inv = 1.0f / fmaxf(sqrtf(ss), 1e-12f);
        float contrib = (acc * inv) * pemb[d];
        #pragma unroll
        for (int off = 32; off; off >>= 1) contrib += __shfl_xor(contrib, off);
        if (d == 0){
          float scale = fminf(__expf(lsc[0]), 100.0f);
          logits[vk] = contrib * scale;
        }
      }
    }
    __syncthreads();
    if (t < 5){
      int v = t;
      float l0 = logits[v*3], l1 = logits[v*3+1], l2 = logits[v*3+2];
      float mm = fmaxf(l0, fmaxf(l1, l2));
      float e0 = __expf(l0-mm), e1 = __expf(l1-mm), e2 = __expf(l2-mm);
      float sm = e0 + e1 + e2;
      wsoft[v*3] = e0/sm; wsoft[v*3+1] = e1/sm; wsoft[v*3+2] = e2/sm;
      out[OUT_RW + v*3 + 0] = l0;
      out[OUT_RW + v*3 + 1] = l1;
      out[OUT_RW + v*3 + 2] = l2;
    }
    return;
  }

  /* ---- blocks 1,2: per-row LSE merge + cons pair, 1 row/thread ---- */
  int r = (blk - 1) * 1024 + t;
  float mp = pmm[r];
  #pragma unroll 8
  for (int k = 1; k < 32; ++k) mp = fmaxf(mp, pmm[k*NN + r]);
  float sp = 0.f;
  #pragma unroll 8
  for (int k = 0; k < 32; ++k) sp += pms[k*NN + r] * __expf(pmm[k*NN + r] - mp);
  float mn = nmm_[r];
  #pragma unroll 8
  for (int k = 1; k < 32; ++k) mn = fmaxf(mn, nmm_[k*NN + r]);
  float sn = 0.f;
  #pragma unroll 8
  for (int k = 0; k < 32; ++k) sn += nms_[k*NN + r] * __expf(nmm_[k*NN + r] - mn);
  float lp = mp + __logf(sp), ln = mn + __logf(sn);
  float mm = fmaxf(lp, ln);
  float ld = mm + __logf(__expf(lp - mm) + __expf(ln - mm));
  bool valid = mp > -1e8f;
  rloss[r]  = valid ? (ld - lp) : 0.f;
  rvalid[r] = valid ? 1 : 0;
  float cs = 0.f;
  if (r < NN - 1){
    const f4* a4 = (const f4*)(E + r*DD);
    const f4* b4 = (const f4*)(E + (r+1)*DD);
    float dot=0.f, na=0.f, nb=0.f;
    #pragma unroll
    for (int q = 0; q < 16; ++q){
      f4 a = a4[q], b = b4[q];
      dot += DOT4(a,b); na += DOT4(a,a); nb += DOT4(b,b);
    }
    float cosv = dot / fmaxf(sqrtf(na)*sqrtf(nb), 1e-8f);
    float t0 = T[r*3]   - T[r*3+3];
    float t1 = T[r*3+1] - T[r*3+4];
    float t2 = T[r*3+2] - T[r*3+5];
    float td = sqrtf(t0*t0 + t1*t1 + t2*t2);
    if (td < 0.1f) cs = fmaxf(0.9f - cosv, 0.f);
  }
  __shared__ float red[1024];
  red[t] = cs;
  __syncthreads();
  for (int off = 512; off; off >>= 1){
    if (t < off) red[t] += red[t + off];
    __syncthreads();
  }
  if (t == 0) consp[blk - 1] = red[0];
}

/* ==================== K3F: reweight (blocks 0..1279) + final reduce (block 1280) ==================== */
__global__ __launch_bounds__(256) void k3f_rwfin(const float* __restrict__ heat,
    const int* __restrict__ peaks, const float* __restrict__ wsoft,
    const float* __restrict__ rloss, const int* __restrict__ rvalid,
    const float* __restrict__ consp,
    float* __restrict__ out){
  int blk = blockIdx.x;
  int t = threadIdx.x;

  if (blk < 1280){
    __shared__ float pr[3], pc[3], w3[3];
    int gid = blk * 256 + t;
    int c = gid >> 16;
    if (t < 3){
      pr[t] = (float)peaks[c*6 + t*2];
      pc[t] = (float)peaks[c*6 + t*2 + 1];
      w3[t] = wsoft[c*3 + t];
    }
    __syncthreads();
    int rem = (gid & 65535) << 2;
    int h = rem >> 9, x0 = rem & 511;
    float bias0=0.f, bias1=0.f, bias2=0.f, bias3=0.f;
    #pragma unroll
    for (int k = 0; k < 3; ++k){
      float dr = (float)h - pr[k];
      float dr2 = dr*dr;
      float w = w3[k];
      float d0 = (float)x0     - pc[k];
      float d1 = (float)(x0+1) - pc[k];
      float d2 = (float)(x0+2) - pc[k];
      float d3 = (float)(x0+3) - pc[k];
      float q0 = dr2 + d0*d0, q1 = dr2 + d1*d1, q2 = dr2 + d2*d2, q3 = dr2 + d3*d3;
      if (q0 < 324.f) bias0 += w * __expf(-q0 * (1.0f/18.0f));
      if (q1 < 324.f) bias1 += w * __expf(-q1 * (1.0f/18.0f));
      if (q2 < 324.f) bias2 += w * __expf(-q2 * (1.0f/18.0f));
      if (q3 < 324.f) bias3 += w * __expf(-q3 * (1.0f/18.0f));
    }
    #pragma unroll
    for (int b = 0; b < NBS; ++b){
      int idx = ((b*NC + c) << 18) + rem;
      f4 hv = *(const f4*)(heat + idx);
      f4 o; o.x = hv.x + bias0; o.y = hv.y + bias1; o.z = hv.z + bias2; o.w = hv.w + bias3;
      *(f4*)(out + idx) = o;
    }
    return;
  }

  /* ---- block 1280: final scalar reduce ---- */
  float s = 0.f; int cnt = 0;
  #pragma unroll
  for (int i = t; i < NN; i += 256){ s += rloss[i]; cnt += rvalid[i]; }
  float cs = (t < 2) ? consp[t] : 0.f;
  __shared__ float r1[256]; __shared__ int r2[256]; __shared__ float r3[256];
  r1[t] = s; r2[t] = cnt; r3[t] = cs;
  __syncthreads();
  for (int off = 128; off; off >>= 1){
    if (t < off){ r1[t] += r1[t+off]; r2[t] += r2[t+off]; r3[t] += r3[t+off]; }
    __syncthreads();
  }
  if (t == 0){
    int c = r2[0] > 1 ? r2[0] : 1;
    out[OUT_RW + 15] = r1[0] / (float)c;
    out[OUT_RW + 16] = r3[0] / (float)(NN - 1);
  }
}

extern "C" void kernel_launch(void* const* d_in, const int* in_sizes, int n_in,
                              void* d_out, int out_size, void* d_ws, size_t ws_size,
                              hipStream_t stream) {
  (void)in_sizes; (void)n_in; (void)out_size; (void)ws_size;
  const float* heat = (const float*)d_in[0];
  const float* fm   = (const float*)d_in[1];
  const float* pemb = (const float*)d_in[2];
  const float* W1   = (const float*)d_in[3];
  const float* b1   = (const float*)d_in[4];
  const float* W2   = (const float*)d_in[5];
  const float* b2   = (const float*)d_in[6];
  const float* lsc  = (const float*)d_in[7];
  const float* E    = (const float*)d_in[8];
  const float* T    = (const float*)d_in[9];
  const void*  pm   = d_in[10];
  const void*  nmm  = d_in[11];
  const void*  hmm  = d_in[12];
  float* out = (float*)d_out;
  char* ws = (char*)d_ws;
  int*   peaks  = (int*)(ws + WS_PEAKS);
  float* wsoft  = (float*)(ws + WS_WSOFT);
  float* btv    = (float*)(ws + WS_BTV);
  int*   bti    = (int*)(ws + WS_BTI);
  float* rloss  = (float*)(ws + WS_RLOSS);
  int*   rvalid = (int*)(ws + WS_RVALID);
  float* consp  = (float*)(ws + WS_CONS);
  float* pmm    = (float*)(ws + WS_PMM);
  float* pms    = (float*)(ws + WS_PMS);
  float* nmm2   = (float*)(ws + WS_NMM);
  float* nms2   = (float*)(ws + WS_NMS);

  hipLaunchKernelGGL(ka_nms_sim, dim3(2304), dim3(256),  0, stream,
                     heat, btv, bti, E, pm, nmm, hmm, pmm, pms, nmm2, nms2);
  hipLaunchKernelGGL(km2,        dim3(3),    dim3(1024), 0, stream,
                     btv, bti, fm, W1, b1, W2, b2, pemb, lsc,
                     pmm, pms, nmm2, nms2, E, T,
                     peaks, wsoft, rloss, rvalid, consp, out);
  hipLaunchKernelGGL(k3f_rwfin,  dim3(1281), dim3(256),  0, stream,
                     heat, peaks, wsoft, rloss, rvalid, consp, out);
}